// Round 5
// baseline (272.358 us; speedup 1.0000x reference)
//
#include <hip/hip_runtime.h>
#include <hip/hip_fp16.h>

typedef _Float16 f16x8 __attribute__((ext_vector_type(8)));
typedef _Float16 f16x4 __attribute__((ext_vector_type(4)));
typedef float    f32x4 __attribute__((ext_vector_type(4)));

#define T_STEPS 32
#define NROWS   10000
#define DDIM    256
#define ROWS_PB 48
#define RPB_B   (ROWS_PB * 512)   // bytes per LDS tile (f16, 512B/row)

// ---------------------------------------------------------------------------
// Pre-kernel: f32 weights -> f16 MFMA B-fragments.
// Fragment (ct,ks), ct=0..15, ks=0..7:
//   dst[((ct*8+ks)*64+lane)*8 + j] = W[ct*16 + (lane&15)][ks*32 + (lane>>4)*8 + j]
// ---------------------------------------------------------------------------
__global__ __launch_bounds__(256) void cvt_weights_kernel(
    const float* __restrict__ Aw, const float* __restrict__ Bw,
    _Float16* __restrict__ wsA, _Float16* __restrict__ wsB)
{
    int tid  = blockIdx.x * 256 + threadIdx.x;      // 0..8191
    int lane = tid & 63;
    int ks   = (tid >> 6) & 7;
    int ct   = tid >> 9;                            // 0..15
    int e     = ct * 16 + (lane & 15);
    int dbase = ks * 32 + (lane >> 4) * 8;
    size_t src = (size_t)e * DDIM + dbase;
    size_t dst = (size_t)tid * 8;
#pragma unroll
    for (int j = 0; j < 8; ++j) {
        wsA[dst + j] = (_Float16)Aw[src + j];
        wsB[dst + j] = (_Float16)Bw[src + j];
    }
}

// Barrier WITHOUT the compiler's vmcnt(0) drain: LDS deps are covered by
// lgkmcnt(0); global stores / prefetch loads keep draining across steps.
__device__ __forceinline__ void barrier_lgkm() {
    asm volatile("s_waitcnt lgkmcnt(0)\n\ts_barrier" ::: "memory");
}

// ---------------------------------------------------------------------------
// Fused SSM. Block = 48 rows x all 32 steps. 16 waves; wave w owns cols
// [16w,16w+16). Weights in registers (64 VGPR/lane). Double-buffered LDS
// H tile + S exchange, ONE lgkm-only barrier per step. Output stored
// DIRECTLY from accumulators (4x64B segments per instr) before the barrier
// so the HBM write drain overlaps the next step's K-loop.
// ---------------------------------------------------------------------------
__global__ __launch_bounds__(1024, 4) void ssm_fused_kernel(
    const float* __restrict__ H,          // [T][N][D] f32
    const _Float16* __restrict__ WaF,     // frag-permuted f16
    const _Float16* __restrict__ WbF,
    const float* __restrict__ bias,       // [D] f32
    float* __restrict__ out)              // [T][N][D] f32
{
    // Hbuf0 | Hbuf1 | Sbuf0 | Sbuf1, each 24 KiB (96 KiB total)
    __shared__ char lds[4 * RPB_B];

    const int tid  = threadIdx.x;
    const int lane = tid & 63;
    const int wave = tid >> 6;            // 0..15 == ct (16-col tile)
    const int lr   = lane & 15;
    const int kg   = lane >> 4;           // 0..3
    const int row0 = blockIdx.x * ROWS_PB;

    // ---- one-time: this wave's weight fragments -> 64 VGPRs ----
    f16x8 wA[8], wB[8];
#pragma unroll
    for (int ks = 0; ks < 8; ++ks) {
        size_t o = (size_t)((wave * 8 + ks) * 64 + lane) * 8;
        wA[ks] = *reinterpret_cast<const f16x8*>(WaF + o);
        wB[ks] = *reinterpret_cast<const f16x8*>(WbF + o);
    }

    // rows this wave stages into LDS (3 rows/wave, clamped for tail block)
    int srow[3];
#pragma unroll
    for (int j = 0; j < 3; ++j) {
        int r = row0 + wave * 3 + j;
        srow[j] = (r < NROWS) ? r : (NROWS - 1);
    }

    const float bv = bias[wave * 16 + lr];

    // ---- prologue: stage H_0 (f32 -> f16, swizzled) into Hbuf0 ----
    f32x4 hreg[3];
#pragma unroll
    for (int j = 0; j < 3; ++j)
        hreg[j] = *reinterpret_cast<const f32x4*>(H + (size_t)srow[j] * DDIM + lane * 4);
#pragma unroll
    for (int j = 0; j < 3; ++j) {
        int r = wave * 3 + j;
        f16x4 v;
#pragma unroll
        for (int k = 0; k < 4; ++k) v[k] = (_Float16)hreg[j][k];
        *reinterpret_cast<f16x4*>(lds + r * 512 + ((lane * 8) ^ ((r & 7) << 4))) = v;
    }
    __syncthreads();

    f32x4 acc[3];

    for (int t = 0; t < T_STEPS; ++t) {
        const int cur = t & 1;
        char* Hc = lds + cur * RPB_B;
        char* Hn = lds + (cur ^ 1) * RPB_B;
        char* Sc = lds + 2 * RPB_B + cur * RPB_B;
        char* Sn = lds + 2 * RPB_B + (cur ^ 1) * RPB_B;
        const bool has_next = (t + 1 < T_STEPS);

        // 1. issue next-step H loads (hidden under this step's K-loop)
        if (has_next) {
            const float* Ht1 = H + (size_t)(t + 1) * NROWS * DDIM;
#pragma unroll
            for (int j = 0; j < 3; ++j)
                hreg[j] = *reinterpret_cast<const f32x4*>(Ht1 + (size_t)srow[j] * DDIM + lane * 4);
        }

        // 2. init acc with bias (C/D: col = lane&15)
#pragma unroll
        for (int nt = 0; nt < 3; ++nt)
#pragma unroll
            for (int i = 0; i < 4; ++i) acc[nt][i] = bv;

        // 3. K-loop: acc += H_t@Wb^T (+ S_{t-1}@Wa^T for t>0). LDS+MFMA only.
        __builtin_amdgcn_s_setprio(1);
#pragma unroll
        for (int ks = 0; ks < 8; ++ks) {
            const int cbyte = ks * 64 + kg * 16;
            f16x8 hfrag[3];
#pragma unroll
            for (int nt = 0; nt < 3; ++nt) {
                int r = nt * 16 + lr;
                hfrag[nt] = *reinterpret_cast<const f16x8*>(
                    Hc + r * 512 + (cbyte ^ ((r & 7) << 4)));
            }
#pragma unroll
            for (int nt = 0; nt < 3; ++nt)
                acc[nt] = __builtin_amdgcn_mfma_f32_16x16x32_f16(hfrag[nt], wB[ks], acc[nt], 0, 0, 0);
            if (t > 0) {
                f16x8 sfrag[3];
#pragma unroll
                for (int nt = 0; nt < 3; ++nt) {
                    int r = nt * 16 + lr;
                    sfrag[nt] = *reinterpret_cast<const f16x8*>(
                        Sc + r * 512 + (cbyte ^ ((r & 7) << 4)));
                }
#pragma unroll
                for (int nt = 0; nt < 3; ++nt)
                    acc[nt] = __builtin_amdgcn_mfma_f32_16x16x32_f16(sfrag[nt], wA[ks], acc[nt], 0, 0, 0);
            }
        }
        __builtin_amdgcn_s_setprio(0);

        // 4a. S_t -> Sn (f16, swizzled) — must complete before the barrier
#pragma unroll
        for (int nt = 0; nt < 3; ++nt) {
            const int c = wave * 16 + lr;
#pragma unroll
            for (int i = 0; i < 4; ++i) {
                int r = nt * 16 + kg * 4 + i;
                *reinterpret_cast<_Float16*>(Sn + r * 512 + ((c * 2) ^ ((r & 7) << 4))) =
                    (_Float16)acc[nt][i];
            }
        }

        // 4b. output stores DIRECT from acc (f32). Per instruction: 16-lane
        //     groups write 4 x 64B row-segments — 64B HBM sectors, no RMW.
        //     Issued before the barrier; drain overlaps next step's K-loop.
        {
            float* Ot = out + (size_t)t * NROWS * DDIM;
            const int c = wave * 16 + lr;
#pragma unroll
            for (int nt = 0; nt < 3; ++nt) {
#pragma unroll
                for (int i = 0; i < 4; ++i) {
                    int gr = row0 + nt * 16 + kg * 4 + i;
                    if (gr < NROWS) Ot[(size_t)gr * DDIM + c] = acc[nt][i];
                }
            }
        }

        // 4c. stage H_{t+1} (f16) into Hn (waits prefetch loads by data dep)
        if (has_next) {
#pragma unroll
            for (int j = 0; j < 3; ++j) {
                int r = wave * 3 + j;
                f16x4 v;
#pragma unroll
                for (int k = 0; k < 4; ++k) v[k] = (_Float16)hreg[j][k];
                *reinterpret_cast<f16x4*>(Hn + r * 512 + ((lane * 8) ^ ((r & 7) << 4))) = v;
            }
        }

        // 5. single lgkm-only barrier: Sn/Hn complete & visible; global
        //    stores keep draining in the background.
        barrier_lgkm();
    }
}

extern "C" void kernel_launch(void* const* d_in, const int* in_sizes, int n_in,
                              void* d_out, int out_size, void* d_ws, size_t ws_size,
                              hipStream_t stream)
{
    const float* H  = (const float*)d_in[0];
    const float* Aw = (const float*)d_in[1];
    const float* Bw = (const float*)d_in[2];
    const float* Bb = (const float*)d_in[3];
    float* out      = (float*)d_out;

    _Float16* wsA = (_Float16*)d_ws;         // 128 KiB
    _Float16* wsB = wsA + 65536;             // 128 KiB

    cvt_weights_kernel<<<32, 256, 0, stream>>>(Aw, Bw, wsA, wsB);

    int nblocks = (NROWS + ROWS_PB - 1) / ROWS_PB;   // 209 (< 256 CUs, 1 round)
    ssm_fused_kernel<<<nblocks, 1024, 0, stream>>>(H, wsA, wsB, Bb, out);
}